// Round 10
// baseline (11232.934 us; speedup 1.0000x reference)
//
#include <hip/hip_runtime.h>
#include <hip/hip_bf16.h>
#include <cstdint>
#include <cstddef>

#define BB 64
#define TT 512
#define DD 1024
#define HH 2048
#define GG 8192   // 4*H

typedef unsigned short u16;
typedef __attribute__((ext_vector_type(8))) short bf16x8;
typedef __attribute__((ext_vector_type(4))) float f32x4;

__device__ __forceinline__ u16 f2bf(float f) {
  union { float f; uint32_t u; } v; v.f = f;
  uint32_t r = v.u + 0x7FFFu + ((v.u >> 16) & 1u);  // RNE
  return (u16)(r >> 16);
}

__device__ __forceinline__ bf16x8 cvt8(const float* __restrict__ p) {
  float4 a = *(const float4*)p;
  float4 b = *(const float4*)(p + 4);
  bf16x8 r;
  r[0] = (short)f2bf(a.x); r[1] = (short)f2bf(a.y);
  r[2] = (short)f2bf(a.z); r[3] = (short)f2bf(a.w);
  r[4] = (short)f2bf(b.x); r[5] = (short)f2bf(b.y);
  r[6] = (short)f2bf(b.z); r[7] = (short)f2bf(b.w);
  return r;
}

// fully-coherent 16B ops (bypass L1+L2, served at coherence point) — PROVEN r5/r9
__device__ __forceinline__ bf16x8 cohload16(const u16* p) {
  bf16x8 v;
  asm volatile("global_load_dwordx4 %0, %1, off sc0 sc1" : "=v"(v) : "v"(p));
  return v;
}
__device__ __forceinline__ void cohstore16(u16* p, bf16x8 v) {
  asm volatile("global_store_dwordx4 %0, %1, off sc0 sc1" :: "v"(p), "v"(v) : "memory");
}
__device__ __forceinline__ int get_xcd() {
  int x;
  asm("s_getreg_b32 %0, hwreg(20, 0, 32)" : "=s"(x));   // HW_REG_XCC_ID
  return x & 7;
}

// ---- preps ----
__global__ void conv_wih_kernel(const float* __restrict__ W, u16* __restrict__ Wb) {
  size_t idx = (size_t)blockIdx.x * blockDim.x + threadIdx.x;
  if (idx >= (size_t)GG * DD / 8) return;
  *(bf16x8*)(Wb + idx * 8) = cvt8(W + idx * 8);
}

// x: [B][T][D] fp32 -> xbT: [T][B][D] bf16
__global__ void conv_xT_kernel(const float* __restrict__ x, u16* __restrict__ xbT) {
  size_t idx = (size_t)blockIdx.x * blockDim.x + threadIdx.x;
  if (idx >= (size_t)BB * TT * DD / 8) return;
  const int col8 = (int)(idx & 127);
  const int row = (int)(idx >> 7);          // b*512 + t
  const int b = row >> 9, t = row & 511;
  bf16x8 v = cvt8(x + (size_t)row * DD + col8 * 8);
  *(bf16x8*)(xbT + ((size_t)t * BB + b) * DD + col8 * 8) = v;
}

// ======================= persistent LSTM =======================
// 256 WGs x 512 thr, 1 WG/CU (146 KB LDS => exactly 32 WGs per XCD).
// Sync = flags only, every flag on its own 64B line (NO atomic RMW anywhere
// except one-time rank election):
//   producer: cohstore h chunk -> vmcnt -> pflag[wg] = t+1
//   importer (rank r in XCD, wave w): wave-parallel poll of group g=r>>2's 32
//     pflags; ONE cohload16/lane (8KB/WG => 2MB/step fabric); plain store ->
//     dirty local L2 (r8-proven); iflag[xcd][r][w] = t
//   consumer wave (m,khalf): wave-parallel poll of the 32 iflags covering
//     (quarter m) x (groups 4kh..4kh+3); buffer_inv sc0 (L1-only); plain loads
//     from LOCAL L2 + MFMA.
// Skew: every WG consumes all 8 groups each step + syncthreads => max skew 1.
//  - staged[p] overwrite at step t races only with reads at t-2 (same parity):
//    importer@t saw pflags>=t => all WGs flagged t-1 => past their (A)-sync of
//    step t-1 => past all staged reads of t-1 and earlier. Safe.
//  - h[p^1] overwrite at end of step t: producer passed its consumer wait of
//    step t => all WGs flagged t => imports of step t-1 (program-order earlier
//    in each WG) complete. Safe.
template<int XMODE>   // 1: x from xbT [T,B,D] bf16; 0: x fp32 [B,T,D] direct
__global__ __launch_bounds__(512, 1)
void lstm_persistent(const float* __restrict__ x, const u16* __restrict__ xbT,
                     const u16* __restrict__ wihb, const float* __restrict__ W_hh,
                     const float* __restrict__ b_ih, const float* __restrict__ b_hh,
                     u16* __restrict__ h0, u16* __restrict__ h1,
                     int* __restrict__ pflag, int* __restrict__ iflag,
                     int* __restrict__ xcdcnt, u16* __restrict__ staged) {
  __shared__ u16 Wlds[64 * 2 * 64 * 8];   // 128 KB  [kb][which][lane][8]
  __shared__ float red[4 * 2 * 64 * 4];   // 8 KB
  __shared__ float gst[64 * 36];          // 9 KB (padded rows)
  __shared__ u16 hsh[2][512];             // 2 KB parity-double-buffered h stage
  __shared__ int sxcd, srank;

  const int tid = threadIdx.x;
  const int wave = tid >> 6, lane = tid & 63;
  const int m = wave & 3, khalf = wave >> 2;
  const int c = lane & 15, lofs = lane >> 4;
  const int wg = blockIdx.x, j0 = wg * 8;

  // ---- one-time: physical XCD + rank election ----
  if (tid == 0) {
    const int xd = get_xcd();
    sxcd = xd;
    srank = __hip_atomic_fetch_add(xcdcnt + xd * 16, 1, __ATOMIC_RELAXED,
                                   __HIP_MEMORY_SCOPE_AGENT);
  }

  // ---- one-time: W_hh slice -> LDS in MFMA fragment order ----
  {
    const int r = tid >> 4;              // local row 0..31 (i,f,g,o x 8)
    const int gr = (r < 8) ? (j0 + r) : (r < 16) ? (HH + j0 + r - 8)
                 : (r < 24) ? (2 * HH + j0 + r - 16) : (3 * HH + j0 + r - 24);
    const int which = r >> 4, cc = r & 15;
    const float* src = W_hh + (size_t)gr * HH;
    const int k0 = (tid & 15) * 128;
    #pragma unroll
    for (int k8 = 0; k8 < 16; ++k8) {
      const int k = k0 + k8 * 8;
      bf16x8 v = cvt8(src + k);
      const int ent = ((k >> 5) * 2 + which) * 64 + ((k >> 3) & 3) * 16 + cc;
      *(bf16x8*)(Wlds + (size_t)ent * 8) = v;
    }
  }

  const int tb = tid >> 3, tj = tid & 7;
  const int jg = j0 + tj;
  const float bia = b_ih[jg] + b_hh[jg];
  const float bfa = b_ih[HH + jg] + b_hh[HH + jg];
  const float bga = b_ih[2 * HH + jg] + b_hh[2 * HH + jg];
  const float boa = b_ih[3 * HH + jg] + b_hh[3 * HH + jg];
  float cst = 0.f;

  const int arow = m * 16 + c;
  const int r0 = (c < 8) ? (j0 + c) : (HH + j0 + c - 8);          // i | f rows
  const int r1 = (c < 8) ? (2 * HH + j0 + c) : (3 * HH + j0 + c - 8); // g | o rows

  __syncthreads();
  const int xcd = sxcd, rank = srank & 31;
  const int g_imp = rank >> 2, q_imp = rank & 3;      // import group / quarter
  // importer addressing (per wave): 2 batch rows x 512B of group g_imp's cols
  const int imp_row = q_imp * 16 + 2 * wave + (lane >> 5);
  const int imp_col = g_imp * 256 + (lane & 31) * 8;
  // importer poll: group g_imp's 32 producer flags (one per lane, mirrored)
  const int pf_idx = (g_imp * 32 + (lane & 31)) * 16;
  // consumer poll: iflags of ranks r=(4kh+gi)*4+m, waves w  (32 lines)
  const int cons_gi = (lane >> 3) & 3, cons_w = lane & 7;
  const int cons_rank = (4 * khalf + cons_gi) * 4 + m;
  const int if_idx = ((xcd * 32 + cons_rank) * 8 + cons_w) * 16;
  const int my_if_idx = ((xcd * 32 + rank) * 8 + wave) * 16;

  for (int t = 0; t < TT; ++t) {
    const u16* hs = (t & 1) ? h1 : h0;
    u16* hd = (t & 1) ? h0 : h1;
    u16* stg = staged + ((size_t)xcd * 2 + (t & 1)) * ((size_t)BB * HH);
    f32x4 acc0 = {0.f, 0.f, 0.f, 0.f};
    f32x4 acc1 = {0.f, 0.f, 0.f, 0.f};

    // ---- x-part (h-independent; hides producer tail + flag propagation) ----
    #pragma unroll 4
    for (int i = 0; i < 16; ++i) {
      const int k = khalf * 512 + i * 32 + lofs * 8;
      bf16x8 a;
      if constexpr (XMODE == 1) a = *(const bf16x8*)(xbT + ((size_t)t * BB + arow) * DD + k);
      else                      a = cvt8(x + ((size_t)arow * TT + t) * DD + k);
      bf16x8 b0 = *(const bf16x8*)(wihb + (size_t)r0 * DD + k);
      bf16x8 b1 = *(const bf16x8*)(wihb + (size_t)r1 * DD + k);
      acc0 = __builtin_amdgcn_mfma_f32_16x16x32_bf16(a, b0, acc0, 0, 0, 0);
      acc1 = __builtin_amdgcn_mfma_f32_16x16x32_bf16(a, b1, acc1, 0, 0, 0);
    }

    if (t > 0) {
      // ---- import: poll 32 producer flags (1 vector load), 1 cohload/lane ----
      {
        int iters = 0;
        while (true) {
          int v = __hip_atomic_load(pflag + pf_idx, __ATOMIC_RELAXED, __HIP_MEMORY_SCOPE_AGENT);
          if (__all(v >= t)) break;
          __builtin_amdgcn_s_sleep(1);
          if (++iters > (1 << 17)) break;   // fail loud, never hang
        }
        asm volatile("" ::: "memory");
        __builtin_amdgcn_sched_barrier(0);
        bf16x8 v = cohload16(hs + (size_t)imp_row * HH + imp_col);
        asm volatile("s_waitcnt vmcnt(0)" ::: "memory");
        *(bf16x8*)(stg + (size_t)imp_row * HH + imp_col) = v;  // dirty local L2
        asm volatile("s_waitcnt vmcnt(0)" ::: "memory");
        if (lane == 0)
          __hip_atomic_store(iflag + my_if_idx, t, __ATOMIC_RELAXED, __HIP_MEMORY_SCOPE_AGENT);
      }
      // ---- consumer gate: poll the 32 iflags of my (quarter, k-half) ----
      {
        int iters = 0;
        while (true) {
          int v = __hip_atomic_load(iflag + if_idx, __ATOMIC_RELAXED, __HIP_MEMORY_SCOPE_AGENT);
          if (__all(v >= t)) break;
          __builtin_amdgcn_s_sleep(1);
          if (++iters > (1 << 17)) break;
        }
        asm volatile("" ::: "memory");
        __builtin_amdgcn_sched_barrier(0);
      }
    }
    // L1-only invalidate so plain loads below see this step's staged lines
    asm volatile("buffer_inv sc0" ::: "memory");
    asm volatile("s_waitcnt vmcnt(0)" ::: "memory");
    __builtin_amdgcn_sched_barrier(0);

    // ---- h-part: plain loads from fresh LOCAL L2, MFMA consume ----
    {
      bf16x8 hf[32];
      const u16* hrow = stg + (size_t)arow * HH + lofs * 8;
      #pragma unroll
      for (int i = 0; i < 32; ++i)
        hf[i] = *(const bf16x8*)(hrow + (size_t)(khalf * 32 + i) * 32);
      #pragma unroll
      for (int i = 0; i < 32; ++i) {
        const int kb = khalf * 32 + i;
        bf16x8 b0 = *(const bf16x8*)(Wlds + (size_t)((kb * 2 + 0) * 64 + lane) * 8);
        bf16x8 b1 = *(const bf16x8*)(Wlds + (size_t)((kb * 2 + 1) * 64 + lane) * 8);
        acc0 = __builtin_amdgcn_mfma_f32_16x16x32_bf16(hf[i], b0, acc0, 0, 0, 0);
        acc1 = __builtin_amdgcn_mfma_f32_16x16x32_bf16(hf[i], b1, acc1, 0, 0, 0);
      }
    }

    // ---- reduce k-halves ----
    if (khalf == 1) {
      #pragma unroll
      for (int q = 0; q < 4; ++q) {
        red[((m * 2 + 0) * 64 + lane) * 4 + q] = acc0[q];
        red[((m * 2 + 1) * 64 + lane) * 4 + q] = acc1[q];
      }
    }
    __syncthreads();                                   // (A)
    if (khalf == 0) {
      #pragma unroll
      for (int q = 0; q < 4; ++q) {
        const float s0 = acc0[q] + red[((m * 2 + 0) * 64 + lane) * 4 + q];
        const float s1 = acc1[q] + red[((m * 2 + 1) * 64 + lane) * 4 + q];
        const int b = m * 16 + lofs * 4 + q;
        gst[b * 36 + c] = s0;        // i (c<8) | f (c>=8)
        gst[b * 36 + 16 + c] = s1;   // g (c<8) | o (c>=8)
      }
    }
    __syncthreads();                                   // (B)

    // ---- gates + state update ----
    {
      const float ip = gst[tb * 36 + tj]      + bia;
      const float fp = gst[tb * 36 + 8 + tj]  + bfa;
      const float gp = gst[tb * 36 + 16 + tj] + bga;
      const float op = gst[tb * 36 + 24 + tj] + boa;
      const float ig = 1.f / (1.f + expf(-ip));
      const float fg = 1.f / (1.f + expf(-fp));
      const float gv = tanhf(gp);
      const float og = 1.f / (1.f + expf(-op));
      cst = fg * cst + ig * gv;
      hsh[t & 1][tb * 8 + tj] = f2bf(og * tanhf(cst));
    }
    __syncthreads();                                   // (C)

    // ---- producer: coherent h store (wave 0) + per-WG flag; rest run ahead ----
    if (tid < 64) {
      bf16x8 v = *(const bf16x8*)(&hsh[t & 1][tid * 8]);
      cohstore16(hd + (size_t)tid * HH + j0, v);
      asm volatile("s_waitcnt vmcnt(0)" ::: "memory");   // data at coherence point
    }
    if (tid == 0)
      __hip_atomic_store(pflag + wg * 16, t + 1, __ATOMIC_RELAXED, __HIP_MEMORY_SCOPE_AGENT);
  }
}

// ======================= fallback per-step kernel (round-1 proven) =======================
__global__ __launch_bounds__(512)
void lstm_step_kernel(const float* __restrict__ x,
                      const float* __restrict__ W_ih, const float* __restrict__ W_hh,
                      const float* __restrict__ b_ih, const float* __restrict__ b_hh,
                      const u16* __restrict__ h_src, u16* __restrict__ h_dst,
                      float* __restrict__ cbuf, int t) {
  const int tid = threadIdx.x;
  const int wave = tid >> 6, lane = tid & 63;
  const int m = wave & 3, khalf = wave >> 2;
  const int j0 = blockIdx.x * 8;
  const int c = lane & 15;
  const int arow = m * 16 + c;
  const int koff = (lane >> 4) * 8;
  const int r0 = (c < 8) ? (j0 + c) : (HH + j0 + c - 8);
  const int r1 = (c < 8) ? (2 * HH + j0 + c) : (3 * HH + j0 + c - 8);

  f32x4 acc0 = {0.f, 0.f, 0.f, 0.f};
  f32x4 acc1 = {0.f, 0.f, 0.f, 0.f};

  if (khalf == 0) {
    const size_t xrow = ((size_t)arow * TT + t) * DD;
    #pragma unroll 4
    for (int kb = 0; kb < 32; ++kb) {
      const int k = kb * 32 + koff;
      bf16x8 a = cvt8(x + xrow + k);
      bf16x8 b0 = cvt8(W_ih + (size_t)r0 * DD + k);
      bf16x8 b1 = cvt8(W_ih + (size_t)r1 * DD + k);
      acc0 = __builtin_amdgcn_mfma_f32_16x16x32_bf16(a, b0, acc0, 0, 0, 0);
      acc1 = __builtin_amdgcn_mfma_f32_16x16x32_bf16(a, b1, acc1, 0, 0, 0);
    }
    #pragma unroll 4
    for (int kb = 0; kb < 16; ++kb) {
      const int kh = kb * 32 + koff;
      bf16x8 a = *(const bf16x8*)(h_src + (size_t)arow * HH + kh);
      bf16x8 b0 = cvt8(W_hh + (size_t)r0 * HH + kh);
      bf16x8 b1 = cvt8(W_hh + (size_t)r1 * HH + kh);
      acc0 = __builtin_amdgcn_mfma_f32_16x16x32_bf16(a, b0, acc0, 0, 0, 0);
      acc1 = __builtin_amdgcn_mfma_f32_16x16x32_bf16(a, b1, acc1, 0, 0, 0);
    }
  } else {
    #pragma unroll 4
    for (int kb = 0; kb < 48; ++kb) {
      const int kh = 512 + kb * 32 + koff;
      bf16x8 a = *(const bf16x8*)(h_src + (size_t)arow * HH + kh);
      bf16x8 b0 = cvt8(W_hh + (size_t)r0 * HH + kh);
      bf16x8 b1 = cvt8(W_hh + (size_t)r1 * HH + kh);
      acc0 = __builtin_amdgcn_mfma_f32_16x16x32_bf16(a, b0, acc0, 0, 0, 0);
      acc1 = __builtin_amdgcn_mfma_f32_16x16x32_bf16(a, b1, acc1, 0, 0, 0);
    }
  }

  __shared__ float red[4][2][64][4];
  if (khalf == 1) {
    #pragma unroll
    for (int q = 0; q < 4; ++q) { red[m][0][lane][q] = acc0[q]; red[m][1][lane][q] = acc1[q]; }
  }
  __syncthreads();
  if (khalf == 1) return;
  #pragma unroll
  for (int q = 0; q < 4; ++q) { acc0[q] += red[m][0][lane][q]; acc1[q] += red[m][1][lane][q]; }

  const float bias0 = b_ih[r0] + b_hh[r0];
  const float bias1 = b_ih[r1] + b_hh[r1];
  #pragma unroll
  for (int q = 0; q < 4; ++q) { acc0[q] += bias0; acc1[q] += bias1; }

  float fpre[4], opre[4];
  #pragma unroll
  for (int q = 0; q < 4; ++q) {
    fpre[q] = __shfl_xor(acc0[q], 8);
    opre[q] = __shfl_xor(acc1[q], 8);
  }

  if (c < 8) {
    const int j = j0 + c;
    #pragma unroll
    for (int q = 0; q < 4; ++q) {
      const int b = m * 16 + (lane >> 4) * 4 + q;
      const float ig = 1.f / (1.f + expf(-acc0[q]));
      const float fg = 1.f / (1.f + expf(-fpre[q]));
      const float gg = tanhf(acc1[q]);
      const float og = 1.f / (1.f + expf(-opre[q]));
      const float cold = cbuf[(size_t)b * HH + j];
      const float cn = fg * cold + ig * gg;
      cbuf[(size_t)b * HH + j] = cn;
      h_dst[(size_t)b * HH + j] = f2bf(og * tanhf(cn));
    }
  }
}

// ======================= head =======================
__global__ __launch_bounds__(256)
void head_kernel(const u16* __restrict__ hfin, const float* __restrict__ W_head,
                 const float* __restrict__ b_head, float* __restrict__ out) {
  const int tid = threadIdx.x, wave = tid >> 6, lane = tid & 63;
  const int m = wave;
  const int c = lane & 15;
  const int koff = (lane >> 4) * 8;
  const int d = blockIdx.x * 16 + c;
  const int arow = m * 16 + c;
  f32x4 acc = {0.f, 0.f, 0.f, 0.f};
  #pragma unroll 4
  for (int kb = 0; kb < 64; ++kb) {
    const int k = kb * 32 + koff;
    bf16x8 a = *(const bf16x8*)(hfin + (size_t)arow * HH + k);
    bf16x8 b = cvt8(W_head + (size_t)d * HH + k);
    acc = __builtin_amdgcn_mfma_f32_16x16x32_bf16(a, b, acc, 0, 0, 0);
  }
  const float bh = b_head[d];
  #pragma unroll
  for (int q = 0; q < 4; ++q) {
    const int b = m * 16 + (lane >> 4) * 4 + q;
    out[(size_t)b * DD + d] = acc[q] + bh;
  }
}

extern "C" void kernel_launch(void* const* d_in, const int* in_sizes, int n_in,
                              void* d_out, int out_size, void* d_ws, size_t ws_size,
                              hipStream_t stream) {
  const float* x      = (const float*)d_in[0];
  const float* W_ih   = (const float*)d_in[1];
  const float* W_hh   = (const float*)d_in[2];
  const float* b_ih   = (const float*)d_in[3];
  const float* b_hh   = (const float*)d_in[4];
  const float* W_head = (const float*)d_in[5];
  const float* b_head = (const float*)d_in[6];
  float* out = (float*)d_out;

  char* ws = (char*)d_ws;
  u16*  h0     = (u16*)(ws + 0);                    // 256 KB
  u16*  h1     = (u16*)(ws + 256 * 1024);           // 256 KB
  int*  pflag  = (int*)(ws + 512 * 1024);           // 256 x 64B producer flags
  int*  iflag  = (int*)(ws + 544 * 1024);           // 8x32x8 x 64B import flags (128 KB)
  int*  xcdcnt = (int*)(ws + 672 * 1024);           // rank counters
  float* cbuf  = (float*)(ws + 512 * 1024);         // fallback only (overlaps flags)
  u16*  staged = (u16*)(ws + (1ull << 20));         // 4 MB: 8 XCD x 2 x 256 KB
  u16*  wihb   = (u16*)(ws + (5ull << 20));         // 16 MB
  u16*  xbT    = (u16*)(ws + (21ull << 20));        // 64 MB

  const size_t NEED1 = (85ull << 20);
  const size_t NEED0 = (21ull << 20);

  // zero h0/h1/flags/counters AND staged (t=0 reads staged as zeros)
  hipMemsetAsync(ws, 0, 5u << 20, stream);

  if (ws_size >= NEED0) {
    {
      const int n8 = (int)((size_t)GG * DD / 8);
      conv_wih_kernel<<<(n8 + 255) / 256, 256, 0, stream>>>(W_ih, wihb);
    }
    if (ws_size >= NEED1) {
      const int n8 = (int)((size_t)BB * TT * DD / 8);
      conv_xT_kernel<<<(n8 + 255) / 256, 256, 0, stream>>>(x, xbT);
      lstm_persistent<1><<<256, 512, 0, stream>>>(x, xbT, wihb, W_hh, b_ih, b_hh,
                                                  h0, h1, pflag, iflag, xcdcnt, staged);
    } else {
      lstm_persistent<0><<<256, 512, 0, stream>>>(x, xbT, wihb, W_hh, b_ih, b_hh,
                                                  h0, h1, pflag, iflag, xcdcnt, staged);
    }
  } else {
    for (int t = 0; t < TT; ++t) {
      u16* hs = (t & 1) ? h1 : h0;
      u16* hd = (t & 1) ? h0 : h1;
      lstm_step_kernel<<<256, 512, 0, stream>>>(x, W_ih, W_hh, b_ih, b_hh, hs, hd, cbuf, t);
    }
  }

  // t=511 (odd) -> final h in h0
  head_kernel<<<64, 256, 0, stream>>>(h0, W_head, b_head, out);
}